// Round 11
// baseline (256.430 us; speedup 1.0000x reference)
//
#include <hip/hip_runtime.h>
#include <math.h>

// MoE router: logits[16384,64] = X[16384,2048] @ W^T, top-2, softmax(2).
// Outputs flat: weights [16384*2] f32, then indices [16384*2] as float.
//
// R9  bf16x6 MFMA path correct (exact 3-way truncating splits, 6 products).
// R10 all staging via global_load_lds, split3 in regs, 4 blk/CU: 55us total.
// R11 fuse reduce into main via last-block ticket (rocPRIM pattern):
//     partials -> threadfence -> atomicAdd(cnt[tg]); ticket==NS-1 block
//     acquires, re-reads 4 slices ASCENDING (deterministic, same order as
//     the proven reduce kernel), top-2 + softmax inline. wsplit zeroes the
//     counters each launch (graph-replay safe). 2 launches instead of 3.

#define NTOK 16384
#define DDIM 2048
#define NEXP 64
#define MBLK 64
#define KC   32
#define NS   4
#define SLICE_ELTS (NTOK * NEXP)

typedef __attribute__((ext_vector_type(8))) short bf16x8;
typedef __attribute__((ext_vector_type(4))) float f32x4;

__device__ static inline void gload_lds16(const void* gsrc, void* ldst) {
    __builtin_amdgcn_global_load_lds(
        (const __attribute__((address_space(1))) void*)gsrc,
        (__attribute__((address_space(3))) void*)ldst, 16, 0, 0);
}

// exact 3-way truncating split: x = h + m + l + r, |r| <= 2^-24 |x|
__device__ static inline void split3(float x, short& h, short& m, short& l) {
    unsigned uh = __float_as_uint(x);
    h = (short)(uh >> 16);
    float r1 = x - __uint_as_float(uh & 0xffff0000u);   // exact
    unsigned um = __float_as_uint(r1);
    m = (short)(um >> 16);
    float r2 = r1 - __uint_as_float(um & 0xffff0000u);  // exact
    l = (short)(__float_as_uint(r2) >> 16);
}

// ---- prep: split W into bf16 h/m/l + zero the tickets (every launch) ----
__global__ __launch_bounds__(256) void wsplit_kernel(
    const float* __restrict__ gw, short* __restrict__ wh,
    short* __restrict__ wm, short* __restrict__ wl, int* __restrict__ cnt)
{
    if (blockIdx.x == 0) cnt[threadIdx.x] = 0;   // 256 token-group tickets
    for (int i = blockIdx.x * 256 + threadIdx.x; i < NEXP * DDIM;
         i += gridDim.x * 256) {
        short h, m, l;
        split3(gw[i], h, m, l);
        wh[i] = h; wm[i] = m; wl[i] = l;
    }
}

// ---- main: partial logits via MFMA bf16x6, split-K + fused reduce ----
__global__ __launch_bounds__(256, 4) void moe_mfma_kernel(
    const float* __restrict__ x,      // [NTOK, DDIM] f32
    const short* __restrict__ wh,     // [NEXP, DDIM] bf16 bits
    const short* __restrict__ wm,
    const short* __restrict__ wl,
    float* __restrict__ part,         // [NS][NTOK][NEXP]
    int* __restrict__ cnt,            // [256] tickets
    float* __restrict__ out)          // weights then indices
{
    // X tile: [64 tok][8 units of 4 f32], phys unit c' holds src col c'^(tok&7).
    // W tile: [64 e][4 units of bf16x8], phys = c ^ (e&3).
    __shared__ float4 XF[2][MBLK * 8];
    __shared__ bf16x8 WH[2][NEXP * 4], WM[2][NEXP * 4], WL[2][NEXP * 4];
    __shared__ int ticket_s;

    const int tid  = threadIdx.x;
    const int lane = tid & 63;
    const int w    = tid >> 6;            // wave 0..3 -> token sub-tile
    const int dsl  = blockIdx.x & (NS - 1);
    const int tg   = blockIdx.x / NS;
    const int T0   = tg * MBLK;
    const int KSL  = DDIM / NS;           // 512
    const int NCH  = KSL / KC;            // 16
    const int k0s  = dsl * KSL;

    // W staging map: thread tid -> e = tid>>2, unit sc = tid&3
    const int we  = tid >> 2;
    const int wsk = ((tid & 3) ^ (we & 3)) * 8;  // source k-offset (shorts)

    // fragment read map: lane l -> row fr, k-group fg
    const int fr  = lane & 15;
    const int fg  = lane >> 4;
    const int fsw = fg ^ (fr & 3);               // W phys unit key
    const int arow = (w * 16 + fr) * 8;          // X row base (units)
    const int akey = fr & 7;                     // X swizzle key (row&7)

    f32x4 acc[4] = {{0.f,0.f,0.f,0.f},{0.f,0.f,0.f,0.f},
                    {0.f,0.f,0.f,0.f},{0.f,0.f,0.f,0.f}};

#define STAGE(ch, buf)                                                        \
    {                                                                         \
        const int kk = k0s + (ch) * KC;                                       \
        _Pragma("unroll")                                                     \
        for (int s = 0; s < 2; ++s) {                                         \
            const int u   = tid + s * 256;                                    \
            const int tok = u >> 3;                                           \
            const int c   = (u & 7) ^ (tok & 7);                              \
            gload_lds16(x + (size_t)(T0 + tok) * DDIM + kk + c * 4,           \
                        &XF[buf][u]);                                         \
        }                                                                     \
        const size_t woff = (size_t)we * DDIM + kk + wsk;                     \
        gload_lds16(wh + woff, &WH[buf][tid]);                                \
        gload_lds16(wm + woff, &WM[buf][tid]);                                \
        gload_lds16(wl + woff, &WL[buf][tid]);                                \
    }

    STAGE(0, 0);
    __syncthreads();

    int cur = 0;
    for (int ch = 0; ch < NCH; ++ch) {
        if (ch + 1 < NCH) STAGE(ch + 1, cur ^ 1);   // async DMA, no registers

        float4 a0 = XF[cur][arow + ((fg * 2 + 0) ^ akey)];
        float4 a1 = XF[cur][arow + ((fg * 2 + 1) ^ akey)];
        bf16x8 ah, am, al;
        {
            float xf8[8] = {a0.x, a0.y, a0.z, a0.w, a1.x, a1.y, a1.z, a1.w};
#pragma unroll
            for (int j = 0; j < 8; ++j) {
                short hj, mj, lj;
                split3(xf8[j], hj, mj, lj);
                ah[j] = hj; am[j] = mj; al[j] = lj;
            }
        }

#pragma unroll
        for (int n = 0; n < 4; ++n) {
            const int bidx = (n * 16 + fr) * 4 + fsw;
            const bf16x8 bh = WH[cur][bidx];
            const bf16x8 bm = WM[cur][bidx];
            const bf16x8 bl = WL[cur][bidx];
            // small products first (rounding), then the big one
            acc[n] = __builtin_amdgcn_mfma_f32_16x16x32_bf16(al, bh, acc[n], 0, 0, 0);
            acc[n] = __builtin_amdgcn_mfma_f32_16x16x32_bf16(am, bm, acc[n], 0, 0, 0);
            acc[n] = __builtin_amdgcn_mfma_f32_16x16x32_bf16(ah, bl, acc[n], 0, 0, 0);
            acc[n] = __builtin_amdgcn_mfma_f32_16x16x32_bf16(am, bh, acc[n], 0, 0, 0);
            acc[n] = __builtin_amdgcn_mfma_f32_16x16x32_bf16(ah, bm, acc[n], 0, 0, 0);
            acc[n] = __builtin_amdgcn_mfma_f32_16x16x32_bf16(ah, bh, acc[n], 0, 0, 0);
        }

        __syncthreads();
        cur ^= 1;
    }
#undef STAGE

    // C/D: col = fr (expert in n-tile), row = fg*4 + j (token in w-tile) [m89]
    float* wsl = part + (size_t)dsl * SLICE_ELTS;
#pragma unroll
    for (int n = 0; n < 4; ++n)
#pragma unroll
        for (int j = 0; j < 4; ++j) {
            const int tok = T0 + w * 16 + fg * 4 + j;
            wsl[(size_t)tok * NEXP + n * 16 + fr] = acc[n][j];
        }

    // ---- last-block ticket: the 4th slice-block of this tg reduces ----
    __threadfence();                       // release: partials -> device scope
    __syncthreads();
    if (tid == 0) ticket_s = atomicAdd(&cnt[tg], 1);
    __syncthreads();
    if (ticket_s != NS - 1) return;

    __threadfence();                       // acquire: see other slices
    if (tid < MBLK) {
        const int t = T0 + tid;            // this thread's token
        float m1 = -INFINITY, m2 = -INFINITY;
        int i1 = 0, i2 = 0;

        const float* base = part + (size_t)t * NEXP;
        for (int e4 = 0; e4 < 16; ++e4) {
            float4 s = *reinterpret_cast<const float4*>(base + e4 * 4);
#pragma unroll
            for (int sl = 1; sl < NS; ++sl) {      // ascending-D order
                float4 p = *reinterpret_cast<const float4*>(
                    base + (size_t)sl * SLICE_ELTS + e4 * 4);
                s.x += p.x; s.y += p.y; s.z += p.z; s.w += p.w;
            }
            float v[4] = {s.x, s.y, s.z, s.w};
#pragma unroll
            for (int q = 0; q < 4; ++q) {
                const int e = e4 * 4 + q;
                if (v[q] > m1) {           // strict '>' = lowest idx on ties
                    m2 = m1; i2 = i1;
                    m1 = v[q]; i1 = e;
                } else if (v[q] > m2) {
                    m2 = v[q]; i2 = e;
                }
            }
        }

        float e2 = expf(m2 - m1);
        float denom = 1.f + e2;
        out[t * 2 + 0] = 1.f / denom;
        out[t * 2 + 1] = e2 / denom;
        out[NTOK * 2 + t * 2 + 0] = (float)i1;
        out[NTOK * 2 + t * 2 + 1] = (float)i2;
    }
}

extern "C" void kernel_launch(void* const* d_in, const int* in_sizes, int n_in,
                              void* d_out, int out_size, void* d_ws, size_t ws_size,
                              hipStream_t stream) {
    const float* x  = (const float*)d_in[0];   // [4,4096,2048] f32
    const float* gw = (const float*)d_in[1];   // [64,2048] f32
    float* out = (float*)d_out;

    // ws layout: Wh|Wm|Wl (3 x 256KB) | cnt (1KB @ 768KB) | part (16MB @ 1MB)
    short* wh  = (short*)d_ws;
    short* wm  = wh + NEXP * DDIM;
    short* wl  = wm + NEXP * DDIM;
    int*   cnt = (int*)((char*)d_ws + 768 * 1024);
    float* part = (float*)((char*)d_ws + (1 << 20));

    wsplit_kernel<<<dim3(128), dim3(256), 0, stream>>>(gw, wh, wm, wl, cnt);
    moe_mfma_kernel<<<dim3((NTOK / MBLK) * NS), dim3(256), 0, stream>>>(
        x, wh, wm, wl, part, cnt, out);
}

// Round 12
// 58.314 us; speedup vs baseline: 4.3974x; 4.3974x over previous
//
#include <hip/hip_runtime.h>
#include <math.h>

// MoE router: logits[16384,64] = X[16384,2048] @ W^T, top-2, softmax(2).
// Outputs flat: weights [16384*2] f32, then indices [16384*2] as float.
//
// R9  bf16x6 MFMA (exact 3-way truncating splits, 6 products) -- correct.
// R10 all staging via global_load_lds, split3 in regs, 4 blk/CU: 55us.
// R11 fused reduce via per-block __threadfence(): 280us -- device-scope
//     fence = L2 writeback/inv storm across 8 non-coherent XCD L2s. REVERTED.
// R12 (a) M=32/wave: block = 128 tok x 64 exp, 4 waves, NS=4 -> 512 blocks,
//         2 blk/CU (56KB LDS). 16 LDS reads per 48 MFMA (was 14 per 24):
//         B-reuse doubles, LDS-pipe cycles/CU drop ~40%.
//     (b) W swizzle key (e>>1)&3 (was e&3): each 16-lane phase now covers
//         8 distinct (row-parity, unit) bank groups -> 2 words/bank = free.
//         Fixes the measured 3.7M-cycle 4-way conflict on W fragment reads.

#define NTOK 16384
#define DDIM 2048
#define NEXP 64
#define TBLK 128                   // tokens per block
#define KC   32
#define NS   4
#define SLICE_ELTS (NTOK * NEXP)

typedef __attribute__((ext_vector_type(8))) short bf16x8;
typedef __attribute__((ext_vector_type(4))) float f32x4;

__device__ static inline void gload_lds16(const void* gsrc, void* ldst) {
    __builtin_amdgcn_global_load_lds(
        (const __attribute__((address_space(1))) void*)gsrc,
        (__attribute__((address_space(3))) void*)ldst, 16, 0, 0);
}

// exact 3-way truncating split: x = h + m + l + r, |r| <= 2^-24 |x|
__device__ static inline void split3(float x, short& h, short& m, short& l) {
    unsigned uh = __float_as_uint(x);
    h = (short)(uh >> 16);
    float r1 = x - __uint_as_float(uh & 0xffff0000u);   // exact
    unsigned um = __float_as_uint(r1);
    m = (short)(um >> 16);
    float r2 = r1 - __uint_as_float(um & 0xffff0000u);  // exact
    l = (short)(__float_as_uint(r2) >> 16);
}

// ---- prep: split W into bf16 h/m/l (deterministic, every launch) ----
__global__ __launch_bounds__(256) void wsplit_kernel(
    const float* __restrict__ gw, short* __restrict__ wh,
    short* __restrict__ wm, short* __restrict__ wl)
{
    for (int i = blockIdx.x * 256 + threadIdx.x; i < NEXP * DDIM;
         i += gridDim.x * 256) {
        short h, m, l;
        split3(gw[i], h, m, l);
        wh[i] = h; wm[i] = m; wl[i] = l;
    }
}

// ---- main: partial logits via MFMA bf16x6, split-K ----
__global__ __launch_bounds__(256, 2) void moe_mfma_kernel(
    const float* __restrict__ x,      // [NTOK, DDIM] f32
    const short* __restrict__ wh,     // [NEXP, DDIM] bf16 bits
    const short* __restrict__ wm,
    const short* __restrict__ wl,
    float* __restrict__ part)         // [NS][NTOK][NEXP]
{
    // X tile: [128 tok][8 units f32x4]; phys unit c' holds src col c'^(tok&7).
    // W tile: [64 e][4 units bf16x8];  phys unit c' holds src col c'^((e>>1)&3).
    __shared__ float4 XF[2][TBLK * 8];                     // 2 x 16 KB
    __shared__ bf16x8 WH[2][NEXP * 4], WM[2][NEXP * 4], WL[2][NEXP * 4]; // 24 KB

    const int tid  = threadIdx.x;
    const int lane = tid & 63;
    const int w    = tid >> 6;            // wave 0..3 -> 32-token sub-tile
    const int dsl  = blockIdx.x & (NS - 1);
    const int tg   = blockIdx.x / NS;
    const int T0   = tg * TBLK;
    const int KSL  = DDIM / NS;           // 512
    const int NCH  = KSL / KC;            // 16
    const int k0s  = dsl * KSL;

    // W staging map: thread tid -> e = tid>>2, unit sc = tid&3
    const int we  = tid >> 2;
    const int wsk = ((tid & 3) ^ ((we >> 1) & 3)) * 8;  // src k-offset (shorts)

    // fragment read map: lane l -> row fr, k-group fg
    const int fr  = lane & 15;
    const int fg  = lane >> 4;
    const int fsw = fg ^ ((fr >> 1) & 3);        // W phys unit key (bank-free)
    const int akey = fr & 7;                     // X swizzle key (row&7)

    f32x4 acc[2][4];
#pragma unroll
    for (int mi = 0; mi < 2; ++mi)
#pragma unroll
        for (int n = 0; n < 4; ++n) acc[mi][n] = (f32x4){0.f, 0.f, 0.f, 0.f};

    // staging: X 1024 units (4/thread), W 3 x 256 units (1/thread each)
#define STAGE(ch, buf)                                                        \
    {                                                                         \
        const int kk = k0s + (ch) * KC;                                       \
        _Pragma("unroll")                                                     \
        for (int s = 0; s < 4; ++s) {                                         \
            const int u   = tid + s * 256;                                    \
            const int tok = u >> 3;                                           \
            const int c   = (u & 7) ^ (tok & 7);                              \
            gload_lds16(x + (size_t)(T0 + tok) * DDIM + kk + c * 4,           \
                        &XF[buf][u]);                                         \
        }                                                                     \
        const size_t woff = (size_t)we * DDIM + kk + wsk;                     \
        gload_lds16(wh + woff, &WH[buf][tid]);                                \
        gload_lds16(wm + woff, &WM[buf][tid]);                                \
        gload_lds16(wl + woff, &WL[buf][tid]);                                \
    }

    STAGE(0, 0);
    __syncthreads();

    int cur = 0;
    for (int ch = 0; ch < NCH; ++ch) {
        if (ch + 1 < NCH) STAGE(ch + 1, cur ^ 1);   // async DMA, no registers

        // A fragments for both 16-token m-tiles (static indices, full unroll)
        bf16x8 ah[2], am[2], al[2];
#pragma unroll
        for (int mi = 0; mi < 2; ++mi) {
            const int arow = (w * 32 + mi * 16 + fr) * 8;
            float4 a0 = XF[cur][arow + ((fg * 2 + 0) ^ akey)];
            float4 a1 = XF[cur][arow + ((fg * 2 + 1) ^ akey)];
            float xf8[8] = {a0.x, a0.y, a0.z, a0.w, a1.x, a1.y, a1.z, a1.w};
#pragma unroll
            for (int j = 0; j < 8; ++j) {
                short hj, mj, lj;
                split3(xf8[j], hj, mj, lj);
                ah[mi][j] = hj; am[mi][j] = mj; al[mi][j] = lj;
            }
        }

#pragma unroll
        for (int n = 0; n < 4; ++n) {
            const int bidx = (n * 16 + fr) * 4 + fsw;
            const bf16x8 bh = WH[cur][bidx];
            const bf16x8 bm = WM[cur][bidx];
            const bf16x8 bl = WL[cur][bidx];
#pragma unroll
            for (int mi = 0; mi < 2; ++mi) {   // 2 independent acc chains
                acc[mi][n] = __builtin_amdgcn_mfma_f32_16x16x32_bf16(al[mi], bh, acc[mi][n], 0, 0, 0);
                acc[mi][n] = __builtin_amdgcn_mfma_f32_16x16x32_bf16(am[mi], bm, acc[mi][n], 0, 0, 0);
                acc[mi][n] = __builtin_amdgcn_mfma_f32_16x16x32_bf16(ah[mi], bl, acc[mi][n], 0, 0, 0);
                acc[mi][n] = __builtin_amdgcn_mfma_f32_16x16x32_bf16(am[mi], bh, acc[mi][n], 0, 0, 0);
                acc[mi][n] = __builtin_amdgcn_mfma_f32_16x16x32_bf16(ah[mi], bm, acc[mi][n], 0, 0, 0);
                acc[mi][n] = __builtin_amdgcn_mfma_f32_16x16x32_bf16(ah[mi], bh, acc[mi][n], 0, 0, 0);
            }
        }

        __syncthreads();
        cur ^= 1;
    }
#undef STAGE

    // C/D: col = fr (expert in n-tile), row = fg*4 + j (token in tile) [m89]
    float* wsl = part + (size_t)dsl * SLICE_ELTS;
#pragma unroll
    for (int mi = 0; mi < 2; ++mi)
#pragma unroll
        for (int n = 0; n < 4; ++n)
#pragma unroll
            for (int j = 0; j < 4; ++j) {
                const int tok = T0 + w * 32 + mi * 16 + fg * 4 + j;
                wsl[(size_t)tok * NEXP + n * 16 + fr] = acc[mi][n][j];
            }
}

// ---- reduce: sum slices (ascending), top-2, softmax ----
__global__ __launch_bounds__(128) void moe_reduce_kernel(
    const float* __restrict__ part,   // [NS][NTOK][NEXP]
    float* __restrict__ out)
{
    const int t = blockIdx.x * 128 + threadIdx.x;
    float m1 = -INFINITY, m2 = -INFINITY;
    int i1 = 0, i2 = 0;

    const float* base = part + (size_t)t * NEXP;
    for (int e4 = 0; e4 < 16; ++e4) {
        float4 s = *reinterpret_cast<const float4*>(base + e4 * 4);
#pragma unroll
        for (int sl = 1; sl < NS; ++sl) {
            float4 p = *reinterpret_cast<const float4*>(
                base + (size_t)sl * SLICE_ELTS + e4 * 4);
            s.x += p.x; s.y += p.y; s.z += p.z; s.w += p.w;
        }
        float v[4] = {s.x, s.y, s.z, s.w};
#pragma unroll
        for (int q = 0; q < 4; ++q) {
            const int e = e4 * 4 + q;
            if (v[q] > m1) {              // strict '>' = lowest index on ties
                m2 = m1; i2 = i1;
                m1 = v[q]; i1 = e;
            } else if (v[q] > m2) {
                m2 = v[q]; i2 = e;
            }
        }
    }

    float e2 = expf(m2 - m1);
    float denom = 1.f + e2;
    out[t * 2 + 0] = 1.f / denom;
    out[t * 2 + 1] = e2 / denom;
    out[NTOK * 2 + t * 2 + 0] = (float)i1;
    out[NTOK * 2 + t * 2 + 1] = (float)i2;
}

extern "C" void kernel_launch(void* const* d_in, const int* in_sizes, int n_in,
                              void* d_out, int out_size, void* d_ws, size_t ws_size,
                              hipStream_t stream) {
    const float* x  = (const float*)d_in[0];   // [4,4096,2048] f32
    const float* gw = (const float*)d_in[1];   // [64,2048] f32
    float* out = (float*)d_out;

    // ws layout: Wh|Wm|Wl (3 x 256KB bf16) | partials NS x 4MiB @ 1MB offset
    short* wh = (short*)d_ws;
    short* wm = wh + NEXP * DDIM;
    short* wl = wm + NEXP * DDIM;
    float* part = (float*)((char*)d_ws + (1 << 20));

    wsplit_kernel<<<dim3(128), dim3(256), 0, stream>>>(gw, wh, wm, wl);
    moe_mfma_kernel<<<dim3((NTOK / TBLK) * NS), dim3(256), 0, stream>>>(
        x, wh, wm, wl, part);
    moe_reduce_kernel<<<dim3(NTOK / 128), dim3(128), 0, stream>>>(part, out);
}

// Round 13
// 51.373 us; speedup vs baseline: 4.9916x; 1.1351x over previous
//
#include <hip/hip_runtime.h>
#include <math.h>

// MoE router: logits[16384,64] = X[16384,2048] @ W^T, top-2, softmax(2).
// Outputs flat: weights [16384*2] f32, then indices [16384*2] as float.
//
// R9  bf16x6 MFMA (exact 3-way truncating splits, 6 products) -- correct.
// R10 all-DMA staging, 4 blk/CU: 55us. R11 fence-fused reduce: 280us REVERTED.
// R12 M=32/wave + W bank fix: 58us -- LDS pressure halved but waves halved;
//     the per-chunk __syncthreads vmcnt(0) DRAIN is now the binding cost.
// R13 counted-vmcnt pipeline (T3/T4 minimum form):
//     X triple-buffered (prefetch depth 2, HBM-cold), W double-buffered
//     (depth 1, L2-warm), raw s_barrier + s_waitcnt vmcnt(4) -- never 0 in
//     steady state. Per iter: issue W(ch+1)[3], X(ch+2)[4] -> 11 outstanding;
//     vmcnt(4) certifies the oldest 7 = X(ch+1)+W(ch+1) BEFORE the barrier,
//     so after the barrier all waves' DMA for the next chunk has landed.
//     WAR: X(ch+2) overwrites the buf read in iter ch-1 (behind a barrier);
//     W(ch+1) overwrites the buf read in iter ch-1 likewise. LDS 72KB,
//     2 blk/CU. Compute/fragment machinery unchanged from R12.

#define NTOK 16384
#define DDIM 2048
#define NEXP 64
#define TBLK 128                   // tokens per block
#define KC   32
#define NS   4
#define SLICE_ELTS (NTOK * NEXP)

typedef __attribute__((ext_vector_type(8))) short bf16x8;
typedef __attribute__((ext_vector_type(4))) float f32x4;

__device__ static inline void gload_lds16(const void* gsrc, void* ldst) {
    __builtin_amdgcn_global_load_lds(
        (const __attribute__((address_space(1))) void*)gsrc,
        (__attribute__((address_space(3))) void*)ldst, 16, 0, 0);
}

// exact 3-way truncating split: x = h + m + l + r, |r| <= 2^-24 |x|
__device__ static inline void split3(float x, short& h, short& m, short& l) {
    unsigned uh = __float_as_uint(x);
    h = (short)(uh >> 16);
    float r1 = x - __uint_as_float(uh & 0xffff0000u);   // exact
    unsigned um = __float_as_uint(r1);
    m = (short)(um >> 16);
    float r2 = r1 - __uint_as_float(um & 0xffff0000u);  // exact
    l = (short)(__float_as_uint(r2) >> 16);
}

// ---- prep: split W into bf16 h/m/l (deterministic, every launch) ----
__global__ __launch_bounds__(256) void wsplit_kernel(
    const float* __restrict__ gw, short* __restrict__ wh,
    short* __restrict__ wm, short* __restrict__ wl)
{
    for (int i = blockIdx.x * 256 + threadIdx.x; i < NEXP * DDIM;
         i += gridDim.x * 256) {
        short h, m, l;
        split3(gw[i], h, m, l);
        wh[i] = h; wm[i] = m; wl[i] = l;
    }
}

// ---- main: partial logits via MFMA bf16x6, split-K, counted-vmcnt ----
__global__ __launch_bounds__(256, 2) void moe_mfma_kernel(
    const float* __restrict__ x,      // [NTOK, DDIM] f32
    const short* __restrict__ wh,     // [NEXP, DDIM] bf16 bits
    const short* __restrict__ wm,
    const short* __restrict__ wl,
    float* __restrict__ part)         // [NS][NTOK][NEXP]
{
    // X tile: [128 tok][8 units f32x4]; phys unit c' holds src col c'^(tok&7).
    // W tile: [64 e][4 units bf16x8];  phys unit c' holds src col c'^((e>>1)&3).
    __shared__ float4 XF[3][TBLK * 8];                     // 3 x 16 KB
    __shared__ bf16x8 WH[2][NEXP * 4], WM[2][NEXP * 4], WL[2][NEXP * 4]; // 24 KB

    const int tid  = threadIdx.x;
    const int lane = tid & 63;
    const int w    = tid >> 6;            // wave 0..3 -> 32-token sub-tile
    const int dsl  = blockIdx.x & (NS - 1);
    const int tg   = blockIdx.x / NS;
    const int T0   = tg * TBLK;
    const int KSL  = DDIM / NS;           // 512
    const int NCH  = KSL / KC;            // 16
    const int k0s  = dsl * KSL;

    // W staging map: thread tid -> e = tid>>2, unit sc = tid&3
    const int we  = tid >> 2;
    const int wsk = ((tid & 3) ^ ((we >> 1) & 3)) * 8;  // src k-offset (shorts)

    // fragment read map: lane l -> row fr, k-group fg
    const int fr  = lane & 15;
    const int fg  = lane >> 4;
    const int fsw = fg ^ ((fr >> 1) & 3);        // W phys unit key (bank-free)
    const int akey = fr & 7;                     // X swizzle key (row&7)

    f32x4 acc[2][4];
#pragma unroll
    for (int mi = 0; mi < 2; ++mi)
#pragma unroll
        for (int n = 0; n < 4; ++n) acc[mi][n] = (f32x4){0.f, 0.f, 0.f, 0.f};

    // staging: X 1024 units (4/thread = 4 vmcnt), W 3 units/thread (3 vmcnt)
#define XSTAGE(ch, buf)                                                       \
    {                                                                         \
        const int kk = k0s + (ch) * KC;                                       \
        _Pragma("unroll")                                                     \
        for (int s = 0; s < 4; ++s) {                                         \
            const int u   = tid + s * 256;                                    \
            const int tok = u >> 3;                                           \
            const int c   = (u & 7) ^ (tok & 7);                              \
            gload_lds16(x + (size_t)(T0 + tok) * DDIM + kk + c * 4,           \
                        &XF[buf][u]);                                         \
        }                                                                     \
    }
#define WSTAGE(ch, buf)                                                       \
    {                                                                         \
        const size_t woff = (size_t)we * DDIM + k0s + (ch) * KC + wsk;        \
        gload_lds16(wh + woff, &WH[buf][tid]);                                \
        gload_lds16(wm + woff, &WM[buf][tid]);                                \
        gload_lds16(wl + woff, &WL[buf][tid]);                                \
    }
#define WAIT4 asm volatile("s_waitcnt vmcnt(4)" ::: "memory")
#define WAIT0 asm volatile("s_waitcnt vmcnt(0)" ::: "memory")
#define BAR   __builtin_amdgcn_s_barrier()

    // prologue: X0, W0 (oldest 7), then X1 in flight
    XSTAGE(0, 0); WSTAGE(0, 0); XSTAGE(1, 1);
    WAIT4; BAR;                       // X0+W0 certified block-wide

    for (int ch = 0; ch < NCH; ++ch) {
        const int xb = ch % 3;
        const int wb = ch & 1;
        if (ch + 1 < NCH) WSTAGE(ch + 1, (ch + 1) & 1);
        if (ch + 2 < NCH) XSTAGE(ch + 2, (ch + 2) % 3);

        // A fragments for both 16-token m-tiles (static indices, full unroll)
        const float4* Xc = XF[xb];
        bf16x8 ah[2], am[2], al[2];
#pragma unroll
        for (int mi = 0; mi < 2; ++mi) {
            const int arow = (w * 32 + mi * 16 + fr) * 8;
            float4 a0 = Xc[arow + ((fg * 2 + 0) ^ akey)];
            float4 a1 = Xc[arow + ((fg * 2 + 1) ^ akey)];
            float xf8[8] = {a0.x, a0.y, a0.z, a0.w, a1.x, a1.y, a1.z, a1.w};
#pragma unroll
            for (int j = 0; j < 8; ++j) {
                short hj, mj, lj;
                split3(xf8[j], hj, mj, lj);
                ah[mi][j] = hj; am[mi][j] = mj; al[mi][j] = lj;
            }
        }

#pragma unroll
        for (int n = 0; n < 4; ++n) {
            const int bidx = (n * 16 + fr) * 4 + fsw;
            const bf16x8 bh = WH[wb][bidx];
            const bf16x8 bm = WM[wb][bidx];
            const bf16x8 bl = WL[wb][bidx];
#pragma unroll
            for (int mi = 0; mi < 2; ++mi) {   // 2 independent acc chains
                acc[mi][n] = __builtin_amdgcn_mfma_f32_16x16x32_bf16(al[mi], bh, acc[mi][n], 0, 0, 0);
                acc[mi][n] = __builtin_amdgcn_mfma_f32_16x16x32_bf16(am[mi], bm, acc[mi][n], 0, 0, 0);
                acc[mi][n] = __builtin_amdgcn_mfma_f32_16x16x32_bf16(ah[mi], bl, acc[mi][n], 0, 0, 0);
                acc[mi][n] = __builtin_amdgcn_mfma_f32_16x16x32_bf16(am[mi], bh, acc[mi][n], 0, 0, 0);
                acc[mi][n] = __builtin_amdgcn_mfma_f32_16x16x32_bf16(ah[mi], bm, acc[mi][n], 0, 0, 0);
                acc[mi][n] = __builtin_amdgcn_mfma_f32_16x16x32_bf16(ah[mi], bh, acc[mi][n], 0, 0, 0);
            }
        }

        // certify next chunk's DMA BEFORE the barrier; keep X(ch+2) in flight
        if (ch + 2 < NCH)      { WAIT4; BAR; }
        else if (ch + 1 < NCH) { WAIT0; BAR; }
    }
#undef XSTAGE
#undef WSTAGE
#undef WAIT4
#undef WAIT0
#undef BAR

    // C/D: col = fr (expert in n-tile), row = fg*4 + j (token in tile) [m89]
    float* wsl = part + (size_t)dsl * SLICE_ELTS;
#pragma unroll
    for (int mi = 0; mi < 2; ++mi)
#pragma unroll
        for (int n = 0; n < 4; ++n)
#pragma unroll
            for (int j = 0; j < 4; ++j) {
                const int tok = T0 + w * 32 + mi * 16 + fg * 4 + j;
                wsl[(size_t)tok * NEXP + n * 16 + fr] = acc[mi][n][j];
            }
}

// ---- reduce: sum slices (ascending), top-2, softmax ----
__global__ __launch_bounds__(128) void moe_reduce_kernel(
    const float* __restrict__ part,   // [NS][NTOK][NEXP]
    float* __restrict__ out)
{
    const int t = blockIdx.x * 128 + threadIdx.x;
    float m1 = -INFINITY, m2 = -INFINITY;
    int i1 = 0, i2 = 0;

    const float* base = part + (size_t)t * NEXP;
    for (int e4 = 0; e4 < 16; ++e4) {
        float4 s = *reinterpret_cast<const float4*>(base + e4 * 4);
#pragma unroll
        for (int sl = 1; sl < NS; ++sl) {
            float4 p = *reinterpret_cast<const float4*>(
                base + (size_t)sl * SLICE_ELTS + e4 * 4);
            s.x += p.x; s.y += p.y; s.z += p.z; s.w += p.w;
        }
        float v[4] = {s.x, s.y, s.z, s.w};
#pragma unroll
        for (int q = 0; q < 4; ++q) {
            const int e = e4 * 4 + q;
            if (v[q] > m1) {              // strict '>' = lowest index on ties
                m2 = m1; i2 = i1;
                m1 = v[q]; i1 = e;
            } else if (v[q] > m2) {
                m2 = v[q]; i2 = e;
            }
        }
    }

    float e2 = expf(m2 - m1);
    float denom = 1.f + e2;
    out[t * 2 + 0] = 1.f / denom;
    out[t * 2 + 1] = e2 / denom;
    out[NTOK * 2 + t * 2 + 0] = (float)i1;
    out[NTOK * 2 + t * 2 + 1] = (float)i2;
}

extern "C" void kernel_launch(void* const* d_in, const int* in_sizes, int n_in,
                              void* d_out, int out_size, void* d_ws, size_t ws_size,
                              hipStream_t stream) {
    const float* x  = (const float*)d_in[0];   // [4,4096,2048] f32
    const float* gw = (const float*)d_in[1];   // [64,2048] f32
    float* out = (float*)d_out;

    // ws layout: Wh|Wm|Wl (3 x 256KB bf16) | partials NS x 4MiB @ 1MB offset
    short* wh = (short*)d_ws;
    short* wm = wh + NEXP * DDIM;
    short* wl = wm + NEXP * DDIM;
    float* part = (float*)((char*)d_ws + (1 << 20));

    wsplit_kernel<<<dim3(128), dim3(256), 0, stream>>>(gw, wh, wm, wl);
    moe_mfma_kernel<<<dim3((NTOK / TBLK) * NS), dim3(256), 0, stream>>>(
        x, wh, wm, wl, part);
    moe_reduce_kernel<<<dim3(NTOK / 128), dim3(128), 0, stream>>>(part, out);
}

// Round 14
// 47.592 us; speedup vs baseline: 5.3881x; 1.0794x over previous
//
#include <hip/hip_runtime.h>
#include <math.h>

// MoE router: logits[16384,64] = X[16384,2048] @ W^T, top-2, softmax(2).
// Outputs flat: weights [16384*2] f32, then indices [16384*2] as float.
//
// R9  bf16x6 (3-way truncating split, 6 products): correct, 55-51us era.
// R11 fence-fused reduce: 280us (XCD L2 writeback storm) REVERTED.
// R13 counted-vmcnt pipeline (X 3-buf depth-2, W 2-buf, vmcnt(4)): 51.4us.
//     Cycle audit: VALU ~19us (split3 x6 products), MFMA 13, LDS 12.6,
//     HBM-X 20 -> conversion machinery rivals the memory floor.
// R14 fp16 4-product: 2-level RNE split (h=rne16(x), m=rne16(x-h); x-h is
//     exact by Sterbenz; residual <=2^-24|x|). Products am*bm, am*bh,
//     ah*bm, ah*bh -- dropped terms ~2x2^-24, SAME error class as R9's
//     passing bf16x6. Halves MFMA (48->32/wave/chunk), W splits 3->2,
//     split VALU 7->4 instr/elem. RNE required (truncation -> 2^-11 h-err
//     -> R8's 1.5e-5 failure class). Pipeline counts re-derived: issue
//     W(ch+1)[2] + X(ch+2)[4], outstanding 10, certify oldest 6 -> vmcnt(4)
//     (unchanged). All other structure identical to R13.

#define NTOK 16384
#define DDIM 2048
#define NEXP 64
#define TBLK 128                   // tokens per block
#define KC   32
#define NS   4
#define SLICE_ELTS (NTOK * NEXP)

typedef __attribute__((ext_vector_type(8))) _Float16 f16x8;
typedef __attribute__((ext_vector_type(4))) float f32x4;

__device__ static inline void gload_lds16(const void* gsrc, void* ldst) {
    __builtin_amdgcn_global_load_lds(
        (const __attribute__((address_space(1))) void*)gsrc,
        (__attribute__((address_space(3))) void*)ldst, 16, 0, 0);
}

// 2-level RNE fp16 split: x = h + m + r, |r| <= 2^-24 |x| (x - (float)h exact)
__device__ static inline void split2h(float x, _Float16& h, _Float16& m) {
    h = (_Float16)x;                 // RNE (default rounding)
    float r = x - (float)h;          // exact (Sterbenz)
    m = (_Float16)r;                 // RNE
}

// ---- prep: split W into fp16 h/m (deterministic, every launch) ----
__global__ __launch_bounds__(256) void wsplit_kernel(
    const float* __restrict__ gw, _Float16* __restrict__ wh,
    _Float16* __restrict__ wm)
{
    for (int i = blockIdx.x * 256 + threadIdx.x; i < NEXP * DDIM;
         i += gridDim.x * 256) {
        _Float16 h, m;
        split2h(gw[i], h, m);
        wh[i] = h; wm[i] = m;
    }
}

// ---- main: partial logits via MFMA fp16x4, split-K, counted-vmcnt ----
__global__ __launch_bounds__(256, 2) void moe_mfma_kernel(
    const float* __restrict__ x,      // [NTOK, DDIM] f32
    const _Float16* __restrict__ wh,  // [NEXP, DDIM] fp16
    const _Float16* __restrict__ wm,
    float* __restrict__ part)         // [NS][NTOK][NEXP]
{
    // X tile: [128 tok][8 units f32x4]; phys unit c' holds src col c'^(tok&7).
    // W tile: [64 e][4 units f16x8];  phys unit c' holds src col c'^((e>>1)&3).
    __shared__ float4 XF[3][TBLK * 8];                  // 3 x 16 KB
    __shared__ f16x8  WH[2][NEXP * 4], WM[2][NEXP * 4]; // 2 x 2 x 4 KB

    const int tid  = threadIdx.x;
    const int lane = tid & 63;
    const int w    = tid >> 6;            // wave 0..3 -> 32-token sub-tile
    const int dsl  = blockIdx.x & (NS - 1);
    const int tg   = blockIdx.x / NS;
    const int T0   = tg * TBLK;
    const int KSL  = DDIM / NS;           // 512
    const int NCH  = KSL / KC;            // 16
    const int k0s  = dsl * KSL;

    // W staging map: thread tid -> e = tid>>2, unit sc = tid&3
    const int we  = tid >> 2;
    const int wsk = ((tid & 3) ^ ((we >> 1) & 3)) * 8;  // src k-offset (elems)

    // fragment read map: lane l -> row fr, k-group fg
    const int fr  = lane & 15;
    const int fg  = lane >> 4;
    const int fsw = fg ^ ((fr >> 1) & 3);        // W phys unit key (bank-free)
    const int akey = fr & 7;                     // X swizzle key (row&7)

    f32x4 acc[2][4];
#pragma unroll
    for (int mi = 0; mi < 2; ++mi)
#pragma unroll
        for (int n = 0; n < 4; ++n) acc[mi][n] = (f32x4){0.f, 0.f, 0.f, 0.f};

    // staging: X 1024 units (4/thread = 4 vmcnt), W 2 units/thread (2 vmcnt)
#define XSTAGE(ch, buf)                                                       \
    {                                                                         \
        const int kk = k0s + (ch) * KC;                                       \
        _Pragma("unroll")                                                     \
        for (int s = 0; s < 4; ++s) {                                         \
            const int u   = tid + s * 256;                                    \
            const int tok = u >> 3;                                           \
            const int c   = (u & 7) ^ (tok & 7);                              \
            gload_lds16(x + (size_t)(T0 + tok) * DDIM + kk + c * 4,           \
                        &XF[buf][u]);                                         \
        }                                                                     \
    }
#define WSTAGE(ch, buf)                                                       \
    {                                                                         \
        const size_t woff = (size_t)we * DDIM + k0s + (ch) * KC + wsk;        \
        gload_lds16(wh + woff, &WH[buf][tid]);                                \
        gload_lds16(wm + woff, &WM[buf][tid]);                                \
    }
#define WAIT4 asm volatile("s_waitcnt vmcnt(4)" ::: "memory")
#define WAIT0 asm volatile("s_waitcnt vmcnt(0)" ::: "memory")
#define BAR   __builtin_amdgcn_s_barrier()

    // prologue: X0(4), W0(2) = oldest 6, then X1(4) in flight
    XSTAGE(0, 0); WSTAGE(0, 0); XSTAGE(1, 1);
    WAIT4; BAR;                       // 10 outstanding -> oldest 6 certified

    for (int ch = 0; ch < NCH; ++ch) {
        const int xb = ch % 3;
        const int wb = ch & 1;
        if (ch + 1 < NCH) WSTAGE(ch + 1, (ch + 1) & 1);
        if (ch + 2 < NCH) XSTAGE(ch + 2, (ch + 2) % 3);

        // A fragments: 2-level RNE fp16 split in registers (static indices)
        const float4* Xc = XF[xb];
        f16x8 ah[2], am[2];
#pragma unroll
        for (int mi = 0; mi < 2; ++mi) {
            const int arow = (w * 32 + mi * 16 + fr) * 8;
            float4 a0 = Xc[arow + ((fg * 2 + 0) ^ akey)];
            float4 a1 = Xc[arow + ((fg * 2 + 1) ^ akey)];
            float xf8[8] = {a0.x, a0.y, a0.z, a0.w, a1.x, a1.y, a1.z, a1.w};
#pragma unroll
            for (int j = 0; j < 8; ++j) {
                _Float16 hj, mj;
                split2h(xf8[j], hj, mj);
                ah[mi][j] = hj; am[mi][j] = mj;
            }
        }

#pragma unroll
        for (int n = 0; n < 4; ++n) {
            const int bidx = (n * 16 + fr) * 4 + fsw;
            const f16x8 bh = WH[wb][bidx];
            const f16x8 bm = WM[wb][bidx];
#pragma unroll
            for (int mi = 0; mi < 2; ++mi) {   // 2 independent acc chains
                acc[mi][n] = __builtin_amdgcn_mfma_f32_16x16x32_f16(am[mi], bm, acc[mi][n], 0, 0, 0);
                acc[mi][n] = __builtin_amdgcn_mfma_f32_16x16x32_f16(am[mi], bh, acc[mi][n], 0, 0, 0);
                acc[mi][n] = __builtin_amdgcn_mfma_f32_16x16x32_f16(ah[mi], bm, acc[mi][n], 0, 0, 0);
                acc[mi][n] = __builtin_amdgcn_mfma_f32_16x16x32_f16(ah[mi], bh, acc[mi][n], 0, 0, 0);
            }
        }

        // certify next chunk's DMA BEFORE the barrier; keep X(ch+2) in flight
        if (ch + 2 < NCH)      { WAIT4; BAR; }
        else if (ch + 1 < NCH) { WAIT0; BAR; }
    }
#undef XSTAGE
#undef WSTAGE
#undef WAIT4
#undef WAIT0
#undef BAR

    // C/D: col = fr (expert in n-tile), row = fg*4 + j (token in tile) [m89]
    float* wsl = part + (size_t)dsl * SLICE_ELTS;
#pragma unroll
    for (int mi = 0; mi < 2; ++mi)
#pragma unroll
        for (int n = 0; n < 4; ++n)
#pragma unroll
            for (int j = 0; j < 4; ++j) {
                const int tok = T0 + w * 32 + mi * 16 + fg * 4 + j;
                wsl[(size_t)tok * NEXP + n * 16 + fr] = acc[mi][n][j];
            }
}

// ---- reduce: sum slices (ascending), top-2, softmax ----
__global__ __launch_bounds__(128) void moe_reduce_kernel(
    const float* __restrict__ part,   // [NS][NTOK][NEXP]
    float* __restrict__ out)
{
    const int t = blockIdx.x * 128 + threadIdx.x;
    float m1 = -INFINITY, m2 = -INFINITY;
    int i1 = 0, i2 = 0;

    const float* base = part + (size_t)t * NEXP;
    for (int e4 = 0; e4 < 16; ++e4) {
        float4 s = *reinterpret_cast<const float4*>(base + e4 * 4);
#pragma unroll
        for (int sl = 1; sl < NS; ++sl) {
            float4 p = *reinterpret_cast<const float4*>(
                base + (size_t)sl * SLICE_ELTS + e4 * 4);
            s.x += p.x; s.y += p.y; s.z += p.z; s.w += p.w;
        }
        float v[4] = {s.x, s.y, s.z, s.w};
#pragma unroll
        for (int q = 0; q < 4; ++q) {
            const int e = e4 * 4 + q;
            if (v[q] > m1) {              // strict '>' = lowest index on ties
                m2 = m1; i2 = i1;
                m1 = v[q]; i1 = e;
            } else if (v[q] > m2) {
                m2 = v[q]; i2 = e;
            }
        }
    }

    float e2 = expf(m2 - m1);
    float denom = 1.f + e2;
    out[t * 2 + 0] = 1.f / denom;
    out[t * 2 + 1] = e2 / denom;
    out[NTOK * 2 + t * 2 + 0] = (float)i1;
    out[NTOK * 2 + t * 2 + 1] = (float)i2;
}

extern "C" void kernel_launch(void* const* d_in, const int* in_sizes, int n_in,
                              void* d_out, int out_size, void* d_ws, size_t ws_size,
                              hipStream_t stream) {
    const float* x  = (const float*)d_in[0];   // [4,4096,2048] f32
    const float* gw = (const float*)d_in[1];   // [64,2048] f32
    float* out = (float*)d_out;

    // ws layout: Wh|Wm (2 x 256KB fp16) | partials NS x 4MiB @ 1MB offset
    _Float16* wh = (_Float16*)d_ws;
    _Float16* wm = wh + NEXP * DDIM;
    float* part = (float*)((char*)d_ws + (1 << 20));

    wsplit_kernel<<<dim3(128), dim3(256), 0, stream>>>(gw, wh, wm);
    moe_mfma_kernel<<<dim3((NTOK / TBLK) * NS), dim3(256), 0, stream>>>(
        x, wh, wm, part);
    moe_reduce_kernel<<<dim3(NTOK / 128), dim3(128), 0, stream>>>(part, out);
}

// Round 15
// 44.630 us; speedup vs baseline: 5.7457x; 1.0664x over previous
//
#include <hip/hip_runtime.h>
#include <math.h>

// MoE router: logits[16384,64] = X[16384,2048] @ W^T, top-2, softmax(2).
// Outputs flat: weights [16384*2] f32, then indices [16384*2] as float.
//
// R13 counted-vmcnt pipeline: 51.4us. R14 fp16 4-product (2-level RNE
//     split, Sterbenz-exact residual): 47.6us. Remaining: ~15us fixed
//     overhead (reduce kernel + 33MB partials round-trip + launch gaps).
// R15 fused in-block split-K:
//     256 blocks x 512 thr; 8 waves = 4 K-slices (kg) x 2 token-halves (tq).
//     Block = 64 tok x 64 exp x K=2048; wave = R14's exact M=32 geometry on
//     its 512-d K-slice. Cross-slice reduce in LDS ([4][64][65] f32 padded,
//     ALIASED onto X buffers after the final compute barrier), in-block
//     top-2+softmax ([e][t] scan layout, proven R2-R7). No partials in HBM,
//     no reduce kernel: 2 launches. LDS = 3x32K X (depth-2 counted vmcnt,
//     R13-proven) + 2x(16K+16K) W = 160KB dynamic (AITER-proven size).
//     vmcnt: 8 DMA/thread/iter; steady outstanding 12 -> certify oldest 8
//     via vmcnt(4); iter14 vmcnt(0); iter15 bare barrier (alias WAR).

#define NTOK 16384
#define DDIM 2048
#define NEXP 64
#define TBLK 64                    // tokens per block
#define KC   32
#define NKG  4                     // K-slices per block (one per wave pair)
#define KSL  (DDIM / NKG)          // 512
#define NCH  (KSL / KC)            // 16

typedef __attribute__((ext_vector_type(8))) _Float16 f16x8;
typedef __attribute__((ext_vector_type(4))) float f32x4;

// LDS layout (dynamic, 163840 B):
//   XF: 3 bufs x 2048 float4  @ 0       (98304 B)  [buf][kg][64 tok][8 u]
//   WH: 2 bufs x 1024 f16x8   @ 98304   (32768 B)  [buf][kg][64 e][4 u]
//   WM: 2 bufs x 1024 f16x8   @ 131072  (32768 B)
//   red: [4][64][65] f32      @ 0       (66560 B)  aliased onto XF
#define XF_OFF 0
#define WH_OFF 98304
#define WM_OFF 131072

__device__ static inline void gload_lds16(const void* gsrc, void* ldst) {
    __builtin_amdgcn_global_load_lds(
        (const __attribute__((address_space(1))) void*)gsrc,
        (__attribute__((address_space(3))) void*)ldst, 16, 0, 0);
}

// 2-level RNE fp16 split: x = h + m + r, |r| <= 2^-24 |x| (x-(float)h exact)
__device__ static inline void split2h(float x, _Float16& h, _Float16& m) {
    h = (_Float16)x;
    float r = x - (float)h;
    m = (_Float16)r;
}

// ---- prep: split W into fp16 h/m (deterministic, every launch) ----
__global__ __launch_bounds__(256) void wsplit_kernel(
    const float* __restrict__ gw, _Float16* __restrict__ wh,
    _Float16* __restrict__ wm)
{
    for (int i = blockIdx.x * 256 + threadIdx.x; i < NEXP * DDIM;
         i += gridDim.x * 256) {
        _Float16 h, m;
        split2h(gw[i], h, m);
        wh[i] = h; wm[i] = m;
    }
}

// ---- fused: MFMA fp16x4 split-K + LDS reduce + top-2 + softmax ----
__global__ __launch_bounds__(512, 1) void moe_fused_kernel(
    const float* __restrict__ x,      // [NTOK, DDIM] f32
    const _Float16* __restrict__ wh,  // [NEXP, DDIM] fp16
    const _Float16* __restrict__ wm,
    float* __restrict__ out)          // weights then indices
{
    extern __shared__ char smem[];
    float4* XF = (float4*)(smem + XF_OFF);   // unit = 16 B
    f16x8*  WH = (f16x8*)(smem + WH_OFF);
    f16x8*  WM = (f16x8*)(smem + WM_OFF);
    float*  red = (float*)smem;              // [4][64][65], aliased

    const int tid  = threadIdx.x;
    const int lane = tid & 63;
    const int w    = tid >> 6;            // wave 0..7
    const int kg   = w >> 1;              // K-slice 0..3
    const int tq   = w & 1;               // token half 0..1
    const int T0   = blockIdx.x * TBLK;

    // fragment read map: lane l -> row fr, k-group fg (identical to R14)
    const int fr  = lane & 15;
    const int fg  = lane >> 4;
    const int fsw = fg ^ ((fr >> 1) & 3);        // W phys unit key
    const int akey = fr & 7;                     // X swizzle key

    f32x4 acc[2][4];
#pragma unroll
    for (int mi = 0; mi < 2; ++mi)
#pragma unroll
        for (int n = 0; n < 4; ++n) acc[mi][n] = (f32x4){0.f, 0.f, 0.f, 0.f};

    // ---- staging (per iter i): X 2048 units (4/thr), Wh 1024 (2/thr),
    //      Wm 1024 (2/thr). Strip s = K-slice; swizzles same as R14.
#define XSTAGE(ch, buf)                                                       \
    {                                                                         \
        _Pragma("unroll")                                                     \
        for (int k = 0; k < 4; ++k) {                                         \
            const int u = tid + k * 512;                                      \
            const int s = u >> 9;                                             \
            const int r = (u >> 3) & 63;                                      \
            const int c = (u & 7) ^ (r & 7);                                  \
            gload_lds16(x + (size_t)(T0 + r) * DDIM + s * KSL + (ch) * KC + c * 4, \
                        &XF[(buf) * 2048 + u]);                               \
        }                                                                     \
    }
#define WSTAGE(ch, buf)                                                       \
    {                                                                         \
        _Pragma("unroll")                                                     \
        for (int k = 0; k < 2; ++k) {                                         \
            const int v = tid + k * 512;                                      \
            const int s = v >> 8;                                             \
            const int e = (v >> 2) & 63;                                      \
            const int c = (v & 3) ^ ((e >> 1) & 3);                           \
            const size_t off = (size_t)e * DDIM + s * KSL + (ch) * KC + c * 8;\
            gload_lds16(wh + off, &WH[(buf) * 1024 + v]);                     \
            gload_lds16(wm + off, &WM[(buf) * 1024 + v]);                     \
        }                                                                     \
    }
#define WAIT4 asm volatile("s_waitcnt vmcnt(4)" ::: "memory")
#define WAIT0 asm volatile("s_waitcnt vmcnt(0)" ::: "memory")
#define BAR   __builtin_amdgcn_s_barrier()

    // prologue: X0(4), W0(4) = oldest 8, then X1(4) in flight
    XSTAGE(0, 0); WSTAGE(0, 0); XSTAGE(1, 1);
    WAIT4; BAR;

    for (int ch = 0; ch < NCH; ++ch) {
        const int xb = ch % 3;
        const int wb = ch & 1;
        if (ch + 1 < NCH) WSTAGE(ch + 1, (ch + 1) & 1);
        if (ch + 2 < NCH) XSTAGE(ch + 2, (ch + 2) % 3);

        // A fragments: 2-level RNE fp16 split in registers
        const float4* Xc = &XF[xb * 2048 + kg * 512];
        f16x8 ah[2], am[2];
#pragma unroll
        for (int mi = 0; mi < 2; ++mi) {
            const int arow = (tq * 32 + mi * 16 + fr) * 8;
            float4 a0 = Xc[arow + ((fg * 2 + 0) ^ akey)];
            float4 a1 = Xc[arow + ((fg * 2 + 1) ^ akey)];
            float xf8[8] = {a0.x, a0.y, a0.z, a0.w, a1.x, a1.y, a1.z, a1.w};
#pragma unroll
            for (int j = 0; j < 8; ++j) {
                _Float16 hj, mj;
                split2h(xf8[j], hj, mj);
                ah[mi][j] = hj; am[mi][j] = mj;
            }
        }

        const f16x8* WHc = &WH[wb * 1024 + kg * 256];
        const f16x8* WMc = &WM[wb * 1024 + kg * 256];
#pragma unroll
        for (int n = 0; n < 4; ++n) {
            const int bidx = (n * 16 + fr) * 4 + fsw;
            const f16x8 bh = WHc[bidx];
            const f16x8 bm = WMc[bidx];
#pragma unroll
            for (int mi = 0; mi < 2; ++mi) {
                acc[mi][n] = __builtin_amdgcn_mfma_f32_16x16x32_f16(am[mi], bm, acc[mi][n], 0, 0, 0);
                acc[mi][n] = __builtin_amdgcn_mfma_f32_16x16x32_f16(am[mi], bh, acc[mi][n], 0, 0, 0);
                acc[mi][n] = __builtin_amdgcn_mfma_f32_16x16x32_f16(ah[mi], bm, acc[mi][n], 0, 0, 0);
                acc[mi][n] = __builtin_amdgcn_mfma_f32_16x16x32_f16(ah[mi], bh, acc[mi][n], 0, 0, 0);
            }
        }

        if (ch + 2 < NCH)      { WAIT4; BAR; }
        else if (ch + 1 < NCH) { WAIT0; BAR; }
        else                   { BAR; }      // WAR: red aliases XF
    }
#undef XSTAGE
#undef WSTAGE
#undef WAIT4
#undef WAIT0
#undef BAR

    // ---- epilogue 1: C/D frags -> red[kg][exp][tok] (padded 65) ----
    // C/D: col = fr (expert in n-tile), row = fg*4 + j (token) [m89]
#pragma unroll
    for (int mi = 0; mi < 2; ++mi)
#pragma unroll
        for (int n = 0; n < 4; ++n)
#pragma unroll
            for (int j = 0; j < 4; ++j) {
                const int e = n * 16 + fr;
                const int t = tq * 32 + mi * 16 + fg * 4 + j;
                red[kg * 4160 + e * 65 + t] = acc[mi][n][j];
            }
    __syncthreads();

    // ---- epilogue 2: reduce K-slices ascending (owner-only slots) ----
#pragma unroll
    for (int k = 0; k < 8; ++k) {
        const int q = tid + k * 512;
        const int e = q >> 6;
        const int t = q & 63;
        float s = red[0 * 4160 + e * 65 + t];
#pragma unroll
        for (int sl = 1; sl < NKG; ++sl)
            s += red[sl * 4160 + e * 65 + t];
        red[e * 65 + t] = s;
    }
    __syncthreads();

    // ---- epilogue 3: top-2 + softmax (lane t scans [e][t], conflict-free)
    if (tid < TBLK) {
        const int t = tid;
        float m1 = -INFINITY, m2 = -INFINITY;
        int i1 = 0, i2 = 0;
        for (int e = 0; e < NEXP; ++e) {
            float v = red[e * 65 + t];
            if (v > m1) {              // strict '>' = lowest index on ties
                m2 = m1; i2 = i1;
                m1 = v;  i1 = e;
            } else if (v > m2) {
                m2 = v;  i2 = e;
            }
        }
        float e2 = expf(m2 - m1);
        float denom = 1.f + e2;
        const int gt = T0 + t;
        out[gt * 2 + 0] = 1.f / denom;
        out[gt * 2 + 1] = e2 / denom;
        out[NTOK * 2 + gt * 2 + 0] = (float)i1;
        out[NTOK * 2 + gt * 2 + 1] = (float)i2;
    }
}

extern "C" void kernel_launch(void* const* d_in, const int* in_sizes, int n_in,
                              void* d_out, int out_size, void* d_ws, size_t ws_size,
                              hipStream_t stream) {
    const float* x  = (const float*)d_in[0];   // [4,4096,2048] f32
    const float* gw = (const float*)d_in[1];   // [64,2048] f32
    float* out = (float*)d_out;

    // ws layout: Wh|Wm (2 x 256KB fp16)
    _Float16* wh = (_Float16*)d_ws;
    _Float16* wm = wh + NEXP * DDIM;

    wsplit_kernel<<<dim3(128), dim3(256), 0, stream>>>(gw, wh, wm);
    moe_fused_kernel<<<dim3(NTOK / TBLK), dim3(512), 163840, stream>>>(
        x, wh, wm, out);
}